// Round 21
// baseline (51.589 us; speedup 1.0000x reference)
//
#include <hip/hip_runtime.h>

// PeerNet: out = relu-MLP with per-feature kNN-mean (k=6, 1D) in the middle.
// B=4096, D=1024, H1=128, H2=64, O=2. All fp32.
//
// Pipeline (3 kernels): gemm1 v1 (MFMA f16 hi/lo, in-loop W1 split, 512 thr),
// sort_window v8 (16 elems/thread, 256 thr: LDS passes 6->3, barriers 14->8,
// j<=8 intra-thread; padded 17-stride LDS), tail v3 (MFMA).
// [R19+R20 benches were infra failures on the same pod; retrying identical
//  source. If infra fails again, next round reverts to R17-verbatim.]
//
// Lessons: R2 grid.sync ~30us. R11: rolled loops 2x slower. R12: s-padding
// -65% conflicts. R13: redundant sort regresses (DS-throughput-bound).
// R15: prep fused into gemm1 (-4.9). R17: tail on MFMA (-5.3). R18: gemm1
// n-split null -> gemm1 at L2-BW floor, reverted to v1.

#define NB   4096
#define DIN  1024
#define NH1  128
#define NH2  64

// padded LDS index for 16-word groups spaced 17 -> bank=(17t+q)%32, conflict-free
#define PAD16(p) ((p) + ((p) >> 4))

typedef _Float16 f16x8 __attribute__((ext_vector_type(8)));
typedef _Float16 f16x4 __attribute__((ext_vector_type(4)));
typedef float    f32x4 __attribute__((ext_vector_type(4)));

__device__ __forceinline__ unsigned pack_hl(float x) {
    const _Float16 h = (_Float16)x;
    const _Float16 l = (_Float16)(x - (float)h);
    unsigned short hu, lu;
    __builtin_memcpy(&hu, &h, 2);
    __builtin_memcpy(&lu, &l, 2);
    return (unsigned)hu | ((unsigned)lu << 16);
}

__device__ __forceinline__ void unpack8(const unsigned* __restrict__ p,
                                        f16x8& hv, f16x8& lv) {
#pragma unroll
    for (int q = 0; q < 8; ++q) {
        const unsigned u = p[q];
        const unsigned short hu = (unsigned short)(u & 0xffffu);
        const unsigned short lu = (unsigned short)(u >> 16);
        _Float16 h, l;
        __builtin_memcpy(&h, &hu, 2);
        __builtin_memcpy(&l, &lu, 2);
        hv[q] = h; lv[q] = l;
    }
}

// ---------------------------------------------------------------------------
// GEMM1 via MFMA 16x16x32 f16, hi/lo split (R17 v1 verbatim).
// Grid 256 x 512 threads. In-loop W1 fp32->hi/lo split.
// ---------------------------------------------------------------------------
__global__ __launch_bounds__(512) void gemm1_mfma(const float* __restrict__ x,
                                                  const float* __restrict__ W1,
                                                  const float* __restrict__ b1,
                                                  float* __restrict__ h1T)
{
    __shared__ _Float16 xhi[16 * 1032];
    __shared__ _Float16 xlo[16 * 1032];
    const int tid = threadIdx.x;
    const int m0  = blockIdx.x * 16;

    {   // stage + convert: thread t -> row t>>5, cols (t&31)*4 + i*128
        const int r  = tid >> 5;
        const int kb = (tid & 31) * 4;
#pragma unroll
        for (int i = 0; i < 8; ++i) {
            const int k = kb + i * 128;
            const float4 v = *(const float4*)&x[(size_t)(m0 + r) * DIN + k];
            const _Float16 h0 = (_Float16)v.x, h1 = (_Float16)v.y;
            const _Float16 h2 = (_Float16)v.z, h3 = (_Float16)v.w;
            f16x4 hv = {h0, h1, h2, h3};
            f16x4 lv = {(_Float16)(v.x - (float)h0), (_Float16)(v.y - (float)h1),
                        (_Float16)(v.z - (float)h2), (_Float16)(v.w - (float)h3)};
            *(f16x4*)&xhi[r * 1032 + k] = hv;
            *(f16x4*)&xlo[r * 1032 + k] = lv;
        }
    }
    __syncthreads();

    const int lane = tid & 63;
    const int w    = tid >> 6;          // 0..7 -> n-tile
    const int n0   = w * 16;
    const int fr   = lane & 15;
    const int fq   = lane >> 4;         // 0..3

    f32x4 acc = {0.f, 0.f, 0.f, 0.f};
    const float* __restrict__ wp = &W1[(size_t)(n0 + fr) * DIN + fq * 8];
    const _Float16* xh = &xhi[fr * 1032 + fq * 8];
    const _Float16* xl = &xlo[fr * 1032 + fq * 8];

#pragma unroll 4
    for (int ks = 0; ks < 32; ++ks) {
        const int k = ks * 32;
        const f16x8 ah = *(const f16x8*)&xh[k];
        const f16x8 al = *(const f16x8*)&xl[k];
        const float4 wa = *(const float4*)&wp[k];
        const float4 wb = *(const float4*)&wp[k + 4];
        const float wf[8] = {wa.x, wa.y, wa.z, wa.w, wb.x, wb.y, wb.z, wb.w};
        f16x8 bh, bl;
#pragma unroll
        for (int q = 0; q < 8; ++q) {
            const _Float16 h = (_Float16)wf[q];
            bh[q] = h;
            bl[q] = (_Float16)(wf[q] - (float)h);
        }
        acc = __builtin_amdgcn_mfma_f32_16x16x32_f16(ah, bh, acc, 0, 0, 0);
        acc = __builtin_amdgcn_mfma_f32_16x16x32_f16(ah, bl, acc, 0, 0, 0);
        acc = __builtin_amdgcn_mfma_f32_16x16x32_f16(al, bh, acc, 0, 0, 0);
    }

    const int n = n0 + fr;
    const float bv = b1[n];
    float4 o;
    o.x = fmaxf(acc[0] + bv, 0.f);
    o.y = fmaxf(acc[1] + bv, 0.f);
    o.z = fmaxf(acc[2] + bv, 0.f);
    o.w = fmaxf(acc[3] + bv, 0.f);
    *(float4*)&h1T[(size_t)n * NB + m0 + fq * 4] = o;
}

// ---------------------------------------------------------------------------
// sort_window v8: grid 256 = 128 cols x 2 halves, 256 threads.
// Thread t holds 16 contiguous elements 16t..16t+15 (wave spans 1024).
//   j<=8      : intra-thread CE (VALU)
//   j=16..512 : in-wave __shfl_xor (m = j/16 <= 32)
//   j>=1024   : LDS round-trip -- only 3 passes total (k=2048:1, k=4096:2)
// Barriers: 3x2 + 2 publish = 8 (was 14). Same bitonic CE network ->
// bitwise-identical sorted array. LDS padded 17-stride (conflict-free).
// ---------------------------------------------------------------------------
__global__ __launch_bounds__(256) void sort_window_kernel(const float* __restrict__ h1T,
                                                          float* __restrict__ prtT)
{
    __shared__ float s[PAD16(NB - 1) + 2];
    __shared__ float r_[PAD16(NB - 1) + 2];
    const int t    = threadIdx.x;        // 0..255
    const int col  = blockIdx.x >> 1;
    const int half = blockIdx.x & 1;
    const float* __restrict__ src = h1T + (size_t)col * NB;

    float v[16];
#pragma unroll
    for (int i4 = 0; i4 < 4; ++i4) {
        const float4 a = *(const float4*)&src[16 * t + i4 * 4];
        v[i4 * 4 + 0] = a.x; v[i4 * 4 + 1] = a.y;
        v[i4 * 4 + 2] = a.z; v[i4 * 4 + 3] = a.w;
    }

#define CE(a, b, up)                                        \
    {                                                       \
        const float _x = v[a], _y = v[b];                   \
        v[a] = (up) ? fminf(_x, _y) : fmaxf(_x, _y);        \
        v[b] = (up) ? fmaxf(_x, _y) : fminf(_x, _y);        \
    }
#define INTRA8(up)                                                          \
    CE(0, 8, up); CE(1, 9, up); CE(2, 10, up); CE(3, 11, up);               \
    CE(4, 12, up); CE(5, 13, up); CE(6, 14, up); CE(7, 15, up);             \
    CE(0, 4, up); CE(1, 5, up); CE(2, 6, up); CE(3, 7, up);                 \
    CE(8, 12, up); CE(9, 13, up); CE(10, 14, up); CE(11, 15, up);           \
    CE(0, 2, up); CE(1, 3, up); CE(4, 6, up); CE(5, 7, up);                 \
    CE(8, 10, up); CE(9, 11, up); CE(12, 14, up); CE(13, 15, up);           \
    CE(0, 1, up); CE(2, 3, up); CE(4, 5, up); CE(6, 7, up);                 \
    CE(8, 9, up); CE(10, 11, up); CE(12, 13, up); CE(14, 15, up);

    // ---- k = 2 (j=1): dir = ((i&2)==0) ----
    CE(0, 1, true);  CE(2, 3, false); CE(4, 5, true);   CE(6, 7, false);
    CE(8, 9, true);  CE(10, 11, false); CE(12, 13, true); CE(14, 15, false);
    // ---- k = 4 (j=2,1): dir = ((i&4)==0) ----
    CE(0, 2, true);  CE(1, 3, true);  CE(4, 6, false);  CE(5, 7, false);
    CE(8, 10, true); CE(9, 11, true); CE(12, 14, false); CE(13, 15, false);
    CE(0, 1, true);  CE(2, 3, true);  CE(4, 5, false);  CE(6, 7, false);
    CE(8, 9, true);  CE(10, 11, true); CE(12, 13, false); CE(14, 15, false);
    // ---- k = 8 (j=4,2,1): dir = ((i&8)==0) ----
    CE(0, 4, true);  CE(1, 5, true);  CE(2, 6, true);   CE(3, 7, true);
    CE(8, 12, false); CE(9, 13, false); CE(10, 14, false); CE(11, 15, false);
    CE(0, 2, true);  CE(1, 3, true);  CE(4, 6, true);   CE(5, 7, true);
    CE(8, 10, false); CE(9, 11, false); CE(12, 14, false); CE(13, 15, false);
    CE(0, 1, true);  CE(2, 3, true);  CE(4, 5, true);   CE(6, 7, true);
    CE(8, 9, false); CE(10, 11, false); CE(12, 13, false); CE(14, 15, false);
    // ---- k = 16: dir = ((t&1)==0), j=8..1 intra ----
    {
        const bool up = (t & 1) == 0;
        INTRA8(up)
    }

    // ---- k = 32..4096 ----
#pragma unroll
    for (int k = 32; k <= 4096; k <<= 1) {
        const bool up = (t & (k >> 4)) == 0;    // k=4096 -> t&256 == 0 -> true
        // LDS passes: j >= 1024
#pragma unroll
        for (int j = k >> 1; j >= 1024; j >>= 1) {
            __syncthreads();
#pragma unroll
            for (int i4 = 0; i4 < 4; ++i4) {
                float4 wv = {v[i4 * 4 + 0], v[i4 * 4 + 1],
                             v[i4 * 4 + 2], v[i4 * 4 + 3]};
                *(float4*)&s[17 * t + i4 * 4] = wv;
            }
            __syncthreads();
            const int tp = t ^ (j >> 4);
            const bool keepmin = (((t & (j >> 4)) == 0) == up);
            float p[16];
#pragma unroll
            for (int i4 = 0; i4 < 4; ++i4) {
                const float4 pa = *(const float4*)&s[17 * tp + i4 * 4];
                p[i4 * 4 + 0] = pa.x; p[i4 * 4 + 1] = pa.y;
                p[i4 * 4 + 2] = pa.z; p[i4 * 4 + 3] = pa.w;
            }
#pragma unroll
            for (int q = 0; q < 16; ++q)
                v[q] = keepmin ? fminf(v[q], p[q]) : fmaxf(v[q], p[q]);
        }
        // shuffle passes: j = min(k/2, 512) .. 16
#pragma unroll
        for (int j = ((k >> 1) > 512 ? 512 : (k >> 1)); j >= 16; j >>= 1) {
            const int  m       = j >> 4;
            const bool keepmin = (((t & m) == 0) == up);
#pragma unroll
            for (int q = 0; q < 16; ++q) {
                const float p = __shfl_xor(v[q], m);
                v[q] = keepmin ? fminf(v[q], p) : fmaxf(v[q], p);
            }
        }
        INTRA8(up)
    }
#undef INTRA8
#undef CE

    // ---- publish sorted column to LDS (padded) ----
    __syncthreads();
#pragma unroll
    for (int i4 = 0; i4 < 4; ++i4) {
        float4 wv = {v[i4 * 4 + 0], v[i4 * 4 + 1],
                     v[i4 * 4 + 2], v[i4 * 4 + 3]};
        *(float4*)&s[17 * t + i4 * 4] = wv;
    }
    __syncthreads();

    // ---- stage 2: r_[p] for the thread's 16 sorted positions ------------
    if (v[15] == 0.0f) {
        const float4 z4 = {0.f, 0.f, 0.f, 0.f};
#pragma unroll
        for (int i4 = 0; i4 < 4; ++i4)
            *(float4*)&r_[17 * t + i4 * 4] = z4;
    } else {
        float rr[16];
#pragma unroll
        for (int q = 0; q < 16; ++q) {
            const int  p  = 16 * t + q;
            const float v0 = v[q];
            int l = p, h = p;
            float sum = v0;  // self
#pragma unroll
            for (int it = 0; it < 5; ++it) {
                const int li = (l > 0) ? l - 1 : 0;
                const int ri = (h < NB - 1) ? h + 1 : NB - 1;
                const float sl = s[PAD16(li)];
                const float sr = s[PAD16(ri)];
                const float dl = (l > 0) ? (v0 - sl) : 1e30f;
                const float dr = (h < NB - 1) ? (sr - v0) : 1e30f;
                if (dl <= dr) { sum += sl; l = li; }
                else          { sum += sr; h = ri; }
            }
            rr[q] = sum * (1.0f / 6.0f);
        }
#pragma unroll
        for (int i4 = 0; i4 < 4; ++i4) {
            float4 rv = {rr[i4 * 4 + 0], rr[i4 * 4 + 1],
                         rr[i4 * 4 + 2], rr[i4 * 4 + 3]};
            *(float4*)&r_[17 * t + i4 * 4] = rv;
        }
    }
    __syncthreads();

    // ---- stage 3: per original element (8/thread), interleaved bsearch --
    const float z5 = s[PAD16(5)];   // ==0 iff column has >= 6 zeros
    float v0[8];
    bool  zs[8];
    float key[8];
    int   lo[8], hi[8];
#pragma unroll
    for (int w = 0; w < 8; ++w) {
        const int e = half * 2048 + t + w * 256;
        v0[w]  = src[e];
        zs[w]  = (v0[w] == 0.0f) && (z5 == 0.0f);
        key[w] = zs[w] ? -1.0f : v0[w];
        lo[w]  = 0;
        hi[w]  = NB;
    }
#pragma unroll
    for (int step = 0; step < 12; ++step) {
#pragma unroll
        for (int w = 0; w < 8; ++w) {
            const int mid = (lo[w] + hi[w]) >> 1;
            const float sv = s[PAD16(mid)];
            if (sv < key[w]) lo[w] = mid + 1; else hi[w] = mid;
        }
    }
#pragma unroll
    for (int w = 0; w < 8; ++w) {
        const int e = half * 2048 + t + w * 256;
        const float res = zs[w] ? 0.0f : r_[PAD16(lo[w])];
        prtT[(size_t)col * NB + e] = res;
    }
}

// ---------------------------------------------------------------------------
// tail v3 (512 threads, MFMA; R17 verbatim).
// ---------------------------------------------------------------------------
__global__ __launch_bounds__(512) void tail_kernel(const float* __restrict__ AT,
                                                   const float* __restrict__ Wpr,
                                                   const float* __restrict__ bpr,
                                                   const float* __restrict__ W2,
                                                   const float* __restrict__ b2,
                                                   const float* __restrict__ Wo,
                                                   const float* __restrict__ bo,
                                                   float* __restrict__ out)
{
    __shared__ unsigned Apk[16 * 132];   // pr tile  [m][k], packed hi/lo
    __shared__ unsigned Ppk[16 * 132];   // P tile   [m][n], packed hi/lo
    __shared__ float    Rs[64 * 32];     // GEMM-C partials [g][m*2+o]
    const int tid = threadIdx.x;
    const int m0  = blockIdx.x * 16;

    {   // stage + convert pr tile: thread: k = tid>>2, f = (tid&3)*4
        const int k = tid >> 2;
        const int f = (tid & 3) * 4;
        const float4 v = *(const float4*)&AT[(size_t)k * NB + m0 + f];
        const float vf[4] = {v.x, v.y, v.z, v.w};
#pragma unroll
        for (int j = 0; j < 4; ++j)
            Apk[(f + j) * 132 + k] = pack_hl(vf[j]);
    }
    __syncthreads();

    const int lane = tid & 63;
    const int w    = tid >> 6;     // 0..7
    const int fr   = lane & 15;
    const int fq   = lane >> 4;    // 0..3

    // ---- GEMM A: P = relu(pr @ Wpr^T + bpr) ------------------------------
    {
        const int n0 = w * 16;
        f32x4 acc = {0.f, 0.f, 0.f, 0.f};
        const float*    __restrict__ wp = &Wpr[(size_t)(n0 + fr) * NH1 + fq * 8];
        const unsigned* __restrict__ ap = &Apk[fr * 132 + fq * 8];
#pragma unroll
        for (int ks = 0; ks < 4; ++ks) {
            const int k = ks * 32;
            f16x8 ah, al;
            unpack8(&ap[k], ah, al);
            const float4 wa = *(const float4*)&wp[k];
            const float4 wb = *(const float4*)&wp[k + 4];
            const float wf[8] = {wa.x, wa.y, wa.z, wa.w, wb.x, wb.y, wb.z, wb.w};
            f16x8 bh, bl;
#pragma unroll
            for (int q = 0; q < 8; ++q) {
                const _Float16 h = (_Float16)wf[q];
                bh[q] = h;
                bl[q] = (_Float16)(wf[q] - (float)h);
            }
            acc = __builtin_amdgcn_mfma_f32_16x16x32_f16(ah, bh, acc, 0, 0, 0);
            acc = __builtin_amdgcn_mfma_f32_16x16x32_f16(ah, bl, acc, 0, 0, 0);
            acc = __builtin_amdgcn_mfma_f32_16x16x32_f16(al, bh, acc, 0, 0, 0);
        }
        const int n = n0 + fr;
        const float bv = bpr[n];
#pragma unroll
        for (int j = 0; j < 4; ++j) {
            const float p = fmaxf(acc[j] + bv, 0.f);
            Ppk[(fq * 4 + j) * 132 + n] = pack_hl(p);
        }
    }
    __syncthreads();

    // ---- GEMM B + C: waves 0..3 (N=64) ----------------------------------
    if (w < 4) {
        const int j0 = w * 16;
        f32x4 acc2 = {0.f, 0.f, 0.f, 0.f};
        const float*    __restrict__ w2p = &W2[(size_t)(j0 + fr) * NH1 + fq * 8];
        const unsigned* __restrict__ pp  = &Ppk[fr * 132 + fq * 8];
#pragma unroll
        for (int ks = 0; ks < 4; ++ks) {
            const int k = ks * 32;
            f16x8 ah, al;
            unpack8(&pp[k], ah, al);
            const float4 wa = *(const float4*)&w2p[k];
            const float4 wb = *(const float4*)&w2p[k + 4];
            const float wf[8] = {wa.x, wa.y, wa.z, wa.w, wb.x, wb.y, wb.z, wb.w};
            f16x8 bh, bl;
#pragma unroll
            for (int q = 0; q < 8; ++q) {
                const _Float16 h = (_Float16)wf[q];
                bh[q] = h;
                bl[q] = (_Float16)(wf[q] - (float)h);
            }
            acc2 = __builtin_amdgcn_mfma_f32_16x16x32_f16(ah, bh, acc2, 0, 0, 0);
            acc2 = __builtin_amdgcn_mfma_f32_16x16x32_f16(ah, bl, acc2, 0, 0, 0);
            acc2 = __builtin_amdgcn_mfma_f32_16x16x32_f16(al, bh, acc2, 0, 0, 0);
        }
        const int jj  = j0 + fr;
        const float b2v = b2[jj];
        const float wo0 = Wo[jj];
        const float wo1 = Wo[NH2 + jj];
        const int g = w * 16 + fr;     // 0..63
#pragma unroll
        for (int j = 0; j < 4; ++j) {
            const float h = fmaxf(acc2[j] + b2v, 0.f);
            const int m = fq * 4 + j;
            Rs[g * 32 + m * 2 + 0] = h * wo0;
            Rs[g * 32 + m * 2 + 1] = h * wo1;
        }
    }
    __syncthreads();

    if (tid < 32) {
        const int mm = tid >> 1, o = tid & 1;
        float sum = 0.f;
#pragma unroll
        for (int g = 0; g < 64; ++g) sum += Rs[g * 32 + mm * 2 + o];
        out[(size_t)(m0 + mm) * 2 + o] = sum + bo[o];
    }
}

extern "C" void kernel_launch(void* const* d_in, const int* in_sizes, int n_in,
                              void* d_out, int out_size, void* d_ws, size_t ws_size,
                              hipStream_t stream)
{
    const float* x   = (const float*)d_in[0];
    const float* W1  = (const float*)d_in[1];
    const float* b1  = (const float*)d_in[2];
    const float* Wpr = (const float*)d_in[3];
    const float* bpr = (const float*)d_in[4];
    const float* W2  = (const float*)d_in[5];
    const float* b2  = (const float*)d_in[6];
    const float* Wo  = (const float*)d_in[7];
    const float* bo  = (const float*)d_in[8];

    float* ws     = (float*)d_ws;
    float* h1T    = ws;                               // [128][4096]  2 MB
    float* prtT   = h1T + NH1 * NB;                   // [128][4096]  2 MB

    gemm1_mfma<<<dim3(NB / 16), 512, 0, stream>>>(x, W1, b1, h1T);
    sort_window_kernel<<<dim3(NH1 * 2), 256, 0, stream>>>(h1T, prtT);
    tail_kernel<<<dim3(NB / 16), 512, 0, stream>>>(prtT, Wpr, bpr, W2, b2, Wo, bo,
                                                   (float*)d_out);
}

// Round 22
// 47.297 us; speedup vs baseline: 1.0907x; 1.0907x over previous
//
#include <hip/hip_runtime.h>

// PeerNet: out = relu-MLP with per-feature kNN-mean (k=6, 1D) in the middle.
// B=4096, D=1024, H1=128, H2=64, O=2. All fp32.
//
// FINAL (R17-verbatim, session best 47.2us): gemm1 (MFMA f16 hi/lo, in-loop
// W1 split), sort_window v7 (8 elems/thread, 512 thr, 9-stride padded LDS),
// tail v3 (both tail GEMMs on MFMA f16 hi/lo, packed-u32 LDS tiles).
//
// Session ledger (62.3 -> 47.2):
//  R15 prep fused into gemm1 (-4.9): in-loop hi/lo split free under L2-bound
//  R17 tail GEMMs on MFMA (-5.3)
//  R9/R12 sort: 8-elem/thread hybrid bitonic + bank-conflict padding (-5.5)
// Bracketing results: R13 sort x2-redundant worse (+10, throughput-bound);
//  R21 sort 16-elem/256-thr worse (+4.4, 1 wave/SIMD latency-exposed);
//  R18 gemm1 n-split null (L2-BW floor); R2 coop grid.sync ~30us/sync;
//  R11 rolled loops 2x slower; R14 r_ pad null.

#define NB   4096
#define DIN  1024
#define NH1  128
#define NH2  64

// padded LDS index: 8-word groups spaced 9 words -> bank = (9t+q)%32, free
#define PAD(p) ((p) + ((p) >> 3))

typedef _Float16 f16x8 __attribute__((ext_vector_type(8)));
typedef _Float16 f16x4 __attribute__((ext_vector_type(4)));
typedef float    f32x4 __attribute__((ext_vector_type(4)));

__device__ __forceinline__ unsigned pack_hl(float x) {
    const _Float16 h = (_Float16)x;
    const _Float16 l = (_Float16)(x - (float)h);
    unsigned short hu, lu;
    __builtin_memcpy(&hu, &h, 2);
    __builtin_memcpy(&lu, &l, 2);
    return (unsigned)hu | ((unsigned)lu << 16);
}

__device__ __forceinline__ void unpack8(const unsigned* __restrict__ p,
                                        f16x8& hv, f16x8& lv) {
#pragma unroll
    for (int q = 0; q < 8; ++q) {
        const unsigned u = p[q];
        const unsigned short hu = (unsigned short)(u & 0xffffu);
        const unsigned short lu = (unsigned short)(u >> 16);
        _Float16 h, l;
        __builtin_memcpy(&h, &hu, 2);
        __builtin_memcpy(&l, &lu, 2);
        hv[q] = h; lv[q] = l;
    }
}

// ---------------------------------------------------------------------------
// GEMM1 via MFMA 16x16x32 f16, hi/lo split: h1T[n][m] = relu(x@W1^T + b1)^T.
// Grid 256 x 512 threads. In-loop W1 fp32->hi/lo split.
// ---------------------------------------------------------------------------
__global__ __launch_bounds__(512) void gemm1_mfma(const float* __restrict__ x,
                                                  const float* __restrict__ W1,
                                                  const float* __restrict__ b1,
                                                  float* __restrict__ h1T)
{
    __shared__ _Float16 xhi[16 * 1032];
    __shared__ _Float16 xlo[16 * 1032];
    const int tid = threadIdx.x;
    const int m0  = blockIdx.x * 16;

    {   // stage + convert: thread t -> row t>>5, cols (t&31)*4 + i*128
        const int r  = tid >> 5;
        const int kb = (tid & 31) * 4;
#pragma unroll
        for (int i = 0; i < 8; ++i) {
            const int k = kb + i * 128;
            const float4 v = *(const float4*)&x[(size_t)(m0 + r) * DIN + k];
            const _Float16 h0 = (_Float16)v.x, h1 = (_Float16)v.y;
            const _Float16 h2 = (_Float16)v.z, h3 = (_Float16)v.w;
            f16x4 hv = {h0, h1, h2, h3};
            f16x4 lv = {(_Float16)(v.x - (float)h0), (_Float16)(v.y - (float)h1),
                        (_Float16)(v.z - (float)h2), (_Float16)(v.w - (float)h3)};
            *(f16x4*)&xhi[r * 1032 + k] = hv;
            *(f16x4*)&xlo[r * 1032 + k] = lv;
        }
    }
    __syncthreads();

    const int lane = tid & 63;
    const int w    = tid >> 6;          // 0..7 -> n-tile
    const int n0   = w * 16;
    const int fr   = lane & 15;
    const int fq   = lane >> 4;         // 0..3

    f32x4 acc = {0.f, 0.f, 0.f, 0.f};
    const float* __restrict__ wp = &W1[(size_t)(n0 + fr) * DIN + fq * 8];
    const _Float16* xh = &xhi[fr * 1032 + fq * 8];
    const _Float16* xl = &xlo[fr * 1032 + fq * 8];

#pragma unroll 4
    for (int ks = 0; ks < 32; ++ks) {
        const int k = ks * 32;
        const f16x8 ah = *(const f16x8*)&xh[k];
        const f16x8 al = *(const f16x8*)&xl[k];
        const float4 wa = *(const float4*)&wp[k];
        const float4 wb = *(const float4*)&wp[k + 4];
        const float wf[8] = {wa.x, wa.y, wa.z, wa.w, wb.x, wb.y, wb.z, wb.w};
        f16x8 bh, bl;
#pragma unroll
        for (int q = 0; q < 8; ++q) {
            const _Float16 h = (_Float16)wf[q];
            bh[q] = h;
            bl[q] = (_Float16)(wf[q] - (float)h);
        }
        acc = __builtin_amdgcn_mfma_f32_16x16x32_f16(ah, bh, acc, 0, 0, 0);
        acc = __builtin_amdgcn_mfma_f32_16x16x32_f16(ah, bl, acc, 0, 0, 0);
        acc = __builtin_amdgcn_mfma_f32_16x16x32_f16(al, bh, acc, 0, 0, 0);
    }

    const int n = n0 + fr;
    const float bv = b1[n];
    float4 o;
    o.x = fmaxf(acc[0] + bv, 0.f);
    o.y = fmaxf(acc[1] + bv, 0.f);
    o.z = fmaxf(acc[2] + bv, 0.f);
    o.w = fmaxf(acc[3] + bv, 0.f);
    *(float4*)&h1T[(size_t)n * NB + m0 + fq * 4] = o;
}

// ---------------------------------------------------------------------------
// sort_window v7: grid 256 = 128 cols x 2 halves, 512 threads.
// 8-elem/thread hybrid bitonic; padded 9-stride LDS (2-way aliasing, free).
// ---------------------------------------------------------------------------
__global__ __launch_bounds__(512) void sort_window_kernel(const float* __restrict__ h1T,
                                                          float* __restrict__ prtT)
{
    __shared__ float s[PAD(NB - 1) + 2];    // padded layout
    __shared__ float r_[PAD(NB - 1) + 2];   // padded layout
    const int t    = threadIdx.x;        // 0..511
    const int col  = blockIdx.x >> 1;
    const int half = blockIdx.x & 1;
    const float* __restrict__ src = h1T + (size_t)col * NB;

    float v[8];
    {
        const float4 a = *(const float4*)&src[8 * t];
        const float4 b = *(const float4*)&src[8 * t + 4];
        v[0] = a.x; v[1] = a.y; v[2] = a.z; v[3] = a.w;
        v[4] = b.x; v[5] = b.y; v[6] = b.z; v[7] = b.w;
    }

#define CE(a, b, up)                                        \
    {                                                       \
        const float _x = v[a], _y = v[b];                   \
        v[a] = (up) ? fminf(_x, _y) : fmaxf(_x, _y);        \
        v[b] = (up) ? fmaxf(_x, _y) : fminf(_x, _y);        \
    }

    // ---- k = 2 (j=1) ----
    CE(0, 1, true); CE(2, 3, false); CE(4, 5, true); CE(6, 7, false);
    // ---- k = 4 (j=2,1) ----
    CE(0, 2, true);  CE(1, 3, true);  CE(4, 6, false); CE(5, 7, false);
    CE(0, 1, true);  CE(2, 3, true);  CE(4, 5, false); CE(6, 7, false);

    // ---- k = 8..256: uniform direction per thread ----
#pragma unroll
    for (int k = 8; k <= 256; k <<= 1) {
        const bool up = (t & (k >> 3)) == 0;
#pragma unroll
        for (int j = k >> 1; j >= 8; j >>= 1) {
            const int  m       = j >> 3;
            const bool keepmin = (((t & m) == 0) == up);
#pragma unroll
            for (int q = 0; q < 8; ++q) {
                const float p = __shfl_xor(v[q], m);
                v[q] = keepmin ? fminf(v[q], p) : fmaxf(v[q], p);
            }
        }
        CE(0, 4, up); CE(1, 5, up); CE(2, 6, up); CE(3, 7, up);
        CE(0, 2, up); CE(1, 3, up); CE(4, 6, up); CE(5, 7, up);
        CE(0, 1, up); CE(2, 3, up); CE(4, 5, up); CE(6, 7, up);
    }

    // ---- k = 512..4096: LDS (padded) for j>=512, shfl 256..8, intra 4..1 -
#pragma unroll
    for (int k = 512; k <= 4096; k <<= 1) {
        const bool up = (t & (k >> 3)) == 0;
#pragma unroll
        for (int j = k >> 1; j >= 512; j >>= 1) {
            __syncthreads();
            float4 w0 = {v[0], v[1], v[2], v[3]};
            float4 w1 = {v[4], v[5], v[6], v[7]};
            *(float4*)&s[9 * t]     = w0;      // PAD(8t) = 9t
            *(float4*)&s[9 * t + 4] = w1;
            __syncthreads();
            const int tp = t ^ (j >> 3);
            const float4 pa = *(const float4*)&s[9 * tp];
            const float4 pb = *(const float4*)&s[9 * tp + 4];
            const bool keepmin = (((t & (j >> 3)) == 0) == up);
            const float p[8] = {pa.x, pa.y, pa.z, pa.w, pb.x, pb.y, pb.z, pb.w};
#pragma unroll
            for (int q = 0; q < 8; ++q)
                v[q] = keepmin ? fminf(v[q], p[q]) : fmaxf(v[q], p[q]);
        }
#pragma unroll
        for (int j = 256; j >= 8; j >>= 1) {
            const int  m       = j >> 3;
            const bool keepmin = (((t & m) == 0) == up);
#pragma unroll
            for (int q = 0; q < 8; ++q) {
                const float p = __shfl_xor(v[q], m);
                v[q] = keepmin ? fminf(v[q], p) : fmaxf(v[q], p);
            }
        }
        CE(0, 4, up); CE(1, 5, up); CE(2, 6, up); CE(3, 7, up);
        CE(0, 2, up); CE(1, 3, up); CE(4, 6, up); CE(5, 7, up);
        CE(0, 1, up); CE(2, 3, up); CE(4, 5, up); CE(6, 7, up);
    }
#undef CE

    // ---- publish sorted column to LDS (padded) ----
    __syncthreads();
    {
        float4 w0 = {v[0], v[1], v[2], v[3]};
        float4 w1 = {v[4], v[5], v[6], v[7]};
        *(float4*)&s[9 * t]     = w0;
        *(float4*)&s[9 * t + 4] = w1;
    }
    __syncthreads();

    // ---- stage 2: r_[p] for the thread's 8 sorted positions -------------
    if (v[7] == 0.0f) {
        const float4 z4 = {0.f, 0.f, 0.f, 0.f};
        *(float4*)&r_[9 * t]     = z4;
        *(float4*)&r_[9 * t + 4] = z4;
    } else {
        float rr[8];
#pragma unroll
        for (int q = 0; q < 8; ++q) {
            const int  p  = 8 * t + q;
            const float v0 = v[q];
            int l = p, h = p;
            float sum = v0;  // self
#pragma unroll
            for (int it = 0; it < 5; ++it) {
                const int li = (l > 0) ? l - 1 : 0;
                const int ri = (h < NB - 1) ? h + 1 : NB - 1;
                const float sl = s[PAD(li)];
                const float sr = s[PAD(ri)];
                const float dl = (l > 0) ? (v0 - sl) : 1e30f;
                const float dr = (h < NB - 1) ? (sr - v0) : 1e30f;
                if (dl <= dr) { sum += sl; l = li; }
                else          { sum += sr; h = ri; }
            }
            rr[q] = sum * (1.0f / 6.0f);
        }
        const float4 r0 = {rr[0], rr[1], rr[2], rr[3]};
        const float4 r1 = {rr[4], rr[5], rr[6], rr[7]};
        *(float4*)&r_[9 * t]     = r0;
        *(float4*)&r_[9 * t + 4] = r1;
    }
    __syncthreads();

    // ---- stage 3: per original element, interleaved bsearch + lookup ----
    const float z5 = s[PAD(5)];   // ==0 iff column has >= 6 zeros
    float v0[4];
    bool  zs[4];
    float key[4];
    int   lo[4], hi[4];
#pragma unroll
    for (int w = 0; w < 4; ++w) {
        const int e = half * 2048 + t + w * 512;
        v0[w]  = src[e];
        zs[w]  = (v0[w] == 0.0f) && (z5 == 0.0f);
        key[w] = zs[w] ? -1.0f : v0[w];
        lo[w]  = 0;
        hi[w]  = NB;
    }
#pragma unroll
    for (int step = 0; step < 12; ++step) {
#pragma unroll
        for (int w = 0; w < 4; ++w) {
            const int mid = (lo[w] + hi[w]) >> 1;
            const float sv = s[PAD(mid)];
            if (sv < key[w]) lo[w] = mid + 1; else hi[w] = mid;
        }
    }
#pragma unroll
    for (int w = 0; w < 4; ++w) {
        const int e = half * 2048 + t + w * 512;
        const float res = zs[w] ? 0.0f : r_[PAD(lo[w])];
        prtT[(size_t)col * NB + e] = res;
    }
}

// ---------------------------------------------------------------------------
// tail v3 (512 threads, MFMA): out = (relu(relu(pr@Wpr^T+bpr)@W2^T+b2))@Wo^T+bo
// ---------------------------------------------------------------------------
__global__ __launch_bounds__(512) void tail_kernel(const float* __restrict__ AT,
                                                   const float* __restrict__ Wpr,
                                                   const float* __restrict__ bpr,
                                                   const float* __restrict__ W2,
                                                   const float* __restrict__ b2,
                                                   const float* __restrict__ Wo,
                                                   const float* __restrict__ bo,
                                                   float* __restrict__ out)
{
    __shared__ unsigned Apk[16 * 132];   // pr tile  [m][k], packed hi/lo
    __shared__ unsigned Ppk[16 * 132];   // P tile   [m][n], packed hi/lo
    __shared__ float    Rs[64 * 32];     // GEMM-C partials [g][m*2+o]
    const int tid = threadIdx.x;
    const int m0  = blockIdx.x * 16;

    {   // stage + convert pr tile: thread: k = tid>>2, f = (tid&3)*4
        const int k = tid >> 2;
        const int f = (tid & 3) * 4;
        const float4 v = *(const float4*)&AT[(size_t)k * NB + m0 + f];
        const float vf[4] = {v.x, v.y, v.z, v.w};
#pragma unroll
        for (int j = 0; j < 4; ++j)
            Apk[(f + j) * 132 + k] = pack_hl(vf[j]);
    }
    __syncthreads();

    const int lane = tid & 63;
    const int w    = tid >> 6;     // 0..7
    const int fr   = lane & 15;
    const int fq   = lane >> 4;    // 0..3

    // ---- GEMM A: P = relu(pr @ Wpr^T + bpr) ------------------------------
    {
        const int n0 = w * 16;
        f32x4 acc = {0.f, 0.f, 0.f, 0.f};
        const float*    __restrict__ wp = &Wpr[(size_t)(n0 + fr) * NH1 + fq * 8];
        const unsigned* __restrict__ ap = &Apk[fr * 132 + fq * 8];
#pragma unroll
        for (int ks = 0; ks < 4; ++ks) {
            const int k = ks * 32;
            f16x8 ah, al;
            unpack8(&ap[k], ah, al);
            const float4 wa = *(const float4*)&wp[k];
            const float4 wb = *(const float4*)&wp[k + 4];
            const float wf[8] = {wa.x, wa.y, wa.z, wa.w, wb.x, wb.y, wb.z, wb.w};
            f16x8 bh, bl;
#pragma unroll
            for (int q = 0; q < 8; ++q) {
                const _Float16 h = (_Float16)wf[q];
                bh[q] = h;
                bl[q] = (_Float16)(wf[q] - (float)h);
            }
            acc = __builtin_amdgcn_mfma_f32_16x16x32_f16(ah, bh, acc, 0, 0, 0);
            acc = __builtin_amdgcn_mfma_f32_16x16x32_f16(ah, bl, acc, 0, 0, 0);
            acc = __builtin_amdgcn_mfma_f32_16x16x32_f16(al, bh, acc, 0, 0, 0);
        }
        const int n = n0 + fr;
        const float bv = bpr[n];
#pragma unroll
        for (int j = 0; j < 4; ++j) {
            const float p = fmaxf(acc[j] + bv, 0.f);
            Ppk[(fq * 4 + j) * 132 + n] = pack_hl(p);
        }
    }
    __syncthreads();

    // ---- GEMM B + C: waves 0..3 (N=64) ----------------------------------
    if (w < 4) {
        const int j0 = w * 16;
        f32x4 acc2 = {0.f, 0.f, 0.f, 0.f};
        const float*    __restrict__ w2p = &W2[(size_t)(j0 + fr) * NH1 + fq * 8];
        const unsigned* __restrict__ pp  = &Ppk[fr * 132 + fq * 8];
#pragma unroll
        for (int ks = 0; ks < 4; ++ks) {
            const int k = ks * 32;
            f16x8 ah, al;
            unpack8(&pp[k], ah, al);
            const float4 wa = *(const float4*)&w2p[k];
            const float4 wb = *(const float4*)&w2p[k + 4];
            const float wf[8] = {wa.x, wa.y, wa.z, wa.w, wb.x, wb.y, wb.z, wb.w};
            f16x8 bh, bl;
#pragma unroll
            for (int q = 0; q < 8; ++q) {
                const _Float16 h = (_Float16)wf[q];
                bh[q] = h;
                bl[q] = (_Float16)(wf[q] - (float)h);
            }
            acc2 = __builtin_amdgcn_mfma_f32_16x16x32_f16(ah, bh, acc2, 0, 0, 0);
            acc2 = __builtin_amdgcn_mfma_f32_16x16x32_f16(ah, bl, acc2, 0, 0, 0);
            acc2 = __builtin_amdgcn_mfma_f32_16x16x32_f16(al, bh, acc2, 0, 0, 0);
        }
        const int jj  = j0 + fr;
        const float b2v = b2[jj];
        const float wo0 = Wo[jj];
        const float wo1 = Wo[NH2 + jj];
        const int g = w * 16 + fr;     // 0..63
#pragma unroll
        for (int j = 0; j < 4; ++j) {
            const float h = fmaxf(acc2[j] + b2v, 0.f);
            const int m = fq * 4 + j;
            Rs[g * 32 + m * 2 + 0] = h * wo0;
            Rs[g * 32 + m * 2 + 1] = h * wo1;
        }
    }
    __syncthreads();

    if (tid < 32) {
        const int mm = tid >> 1, o = tid & 1;
        float sum = 0.f;
#pragma unroll
        for (int g = 0; g < 64; ++g) sum += Rs[g * 32 + mm * 2 + o];
        out[(size_t)(m0 + mm) * 2 + o] = sum + bo[o];
    }
}

extern "C" void kernel_launch(void* const* d_in, const int* in_sizes, int n_in,
                              void* d_out, int out_size, void* d_ws, size_t ws_size,
                              hipStream_t stream)
{
    const float* x   = (const float*)d_in[0];
    const float* W1  = (const float*)d_in[1];
    const float* b1  = (const float*)d_in[2];
    const float* Wpr = (const float*)d_in[3];
    const float* bpr = (const float*)d_in[4];
    const float* W2  = (const float*)d_in[5];
    const float* b2  = (const float*)d_in[6];
    const float* Wo  = (const float*)d_in[7];
    const float* bo  = (const float*)d_in[8];

    float* ws     = (float*)d_ws;
    float* h1T    = ws;                               // [128][4096]  2 MB
    float* prtT   = h1T + NH1 * NB;                   // [128][4096]  2 MB

    gemm1_mfma<<<dim3(NB / 16), 512, 0, stream>>>(x, W1, b1, h1T);
    sort_window_kernel<<<dim3(NH1 * 2), 512, 0, stream>>>(h1T, prtT);
    tail_kernel<<<dim3(NB / 16), 512, 0, stream>>>(prtT, Wpr, bpr, W2, b2, Wo, bo,
                                                   (float*)d_out);
}